// Round 8
// baseline (313.708 us; speedup 1.0000x reference)
//
#include <hip/hip_runtime.h>
#include <cstdint>
#include <cstddef>

#define B_ 2
#define S_ 4096
#define T_ 4096
#define D_ 512
#define W_ 128

// degree-4 poly in t=z^2 for h(t) = silu(z) - z/2, fit on t in [0, 6.25]
#define A0C (-0.0006958f)
#define A1C (0.2529946f)
#define A2C (-0.0226345f)
#define A3C (0.0022173f)
#define A4C (-0.00011668f)
#define ZCUT 2.5f
#define ROWCAP 65536

typedef __attribute__((ext_vector_type(8))) short bf16x8;
typedef __attribute__((ext_vector_type(4))) float f32x4;

__device__ __forceinline__ uint16_t f2bf(float f){
  uint32_t u = __float_as_uint(f);
  u += 0x7FFFu + ((u >> 16) & 1u);        // round-to-nearest-even
  return (uint16_t)(u >> 16);
}
__device__ __forceinline__ float bf2f(uint16_t h){
  return __uint_as_float(((uint32_t)h) << 16);
}

__device__ __forceinline__ void gl_lds16(const void* g, void* l){
  __builtin_amdgcn_global_load_lds(
      (const __attribute__((address_space(1))) void*)g,
      (__attribute__((address_space(3))) void*)l, 16, 0, 0);
}

union F4 { float4 v; float f[4]; };

// ---- prep: transpose weights (coalesced WRITES, scattered L2 reads),
//      convert small vecs, cbias, zero maxT + rowCnt.  32 blocks.
template<int INBF>
__global__ void prep_k(const void* __restrict__ Ws, const void* __restrict__ Wt,
                       const void* __restrict__ wso, const void* __restrict__ wto,
                       const void* __restrict__ wi, const void* __restrict__ bias,
                       float* __restrict__ WsT, float* __restrict__ WtT,
                       float* __restrict__ wsof, float* __restrict__ wtof,
                       float* __restrict__ wif, float* __restrict__ cbias,
                       float* __restrict__ maxT, int* __restrict__ rowCnt){
  auto cv = [](const void* p, int i)->float{
    if (INBF) return bf2f(((const uint16_t*)p)[i]);
    return ((const float*)p)[i];
  };
  const void* in = (blockIdx.x & 1) ? Wt : Ws;
  float* out = (blockIdx.x & 1) ? WtT : WsT;
  int base = (blockIdx.x >> 1) * 4096;
  for (int o = base + threadIdx.x; o < base + 4096; o += blockDim.x){
    int d = o >> 7, w = o & (W_ - 1);
    out[o] = cv(in, w * D_ + d);          // write linear/coalesced
  }
  if (blockIdx.x == 1){
    maxT[threadIdx.x] = 0.f;              // B_*W_ = 256 entries
  }
  if (blockIdx.x == 0){
    if (threadIdx.x < W_){
      wsof[threadIdx.x] = cv(wso, threadIdx.x);
      wtof[threadIdx.x] = cv(wto, threadIdx.x);
      wif[threadIdx.x]  = cv(wi,  threadIdx.x);
    }
    __syncthreads();
    if (threadIdx.x == 0){
      float s = 0.f;
      for (int k = 0; k < W_; ++k) s += wif[k];
      cbias[0] = cv(bias, 0) + A0C * s;
      rowCnt[0] = 0;
    }
  }
}

// ---- fused projection: raw input -> pT (transposed), lin, bf16 features
// 16 rows/block (512 blocks, 2 waves/SIMD).  MODE 0 = source (features
// scaled by w_int + poly coeffs), MODE 1 = target (+ fused maxT atomicMax)
template<int INBF, int MODE>
__global__ __launch_bounds__(256) void proj_k(const void* __restrict__ xraw,
        const float* __restrict__ WT, const float* __restrict__ wout,
        const float* __restrict__ wint,
        float* __restrict__ pT, float* __restrict__ lin,
        uint16_t* __restrict__ feat, float* __restrict__ maxT){
  __shared__ float xl[64 * 18];
  __shared__ float wl[64 * 128];
  int tid = threadIdx.x;
  int tx = tid & 31, ty = tid >> 5;
  int rowBase = blockIdx.x * 16;
  float acc[2][4] = {};
  for (int c = 0; c < 8; ++c){
    int d0 = c * 64;
    const float4* wt4 = (const float4*)(WT + (size_t)d0 * W_);
    float4* wl4 = (float4*)wl;
    #pragma unroll
    for (int p = 0; p < 8; ++p){ int q = tid + 256 * p; wl4[q] = wt4[q]; }
    {
      int q = tid;
      int r = q >> 4, dq = q & 15;
      float v0, v1, v2, v3;
      if (INBF){
        const uint16_t* xp = (const uint16_t*)xraw + (size_t)(rowBase + r) * D_ + d0 + dq * 4;
        ushort4 u = *(const ushort4*)xp;
        v0 = bf2f(u.x); v1 = bf2f(u.y); v2 = bf2f(u.z); v3 = bf2f(u.w);
      } else {
        const float* xp = (const float*)xraw + (size_t)(rowBase + r) * D_ + d0 + dq * 4;
        float4 u = *(const float4*)xp;
        v0 = u.x; v1 = u.y; v2 = u.z; v3 = u.w;
      }
      xl[(dq*4+0)*18 + r] = v0;
      xl[(dq*4+1)*18 + r] = v1;
      xl[(dq*4+2)*18 + r] = v2;
      xl[(dq*4+3)*18 + r] = v3;
    }
    __syncthreads();
    #pragma unroll 4
    for (int d = 0; d < 64; ++d){
      float a0 = xl[d * 18 + ty * 2 + 0];
      float a1 = xl[d * 18 + ty * 2 + 1];
      F4 w;
      w.v = *(const float4*)(wl + d * 128 + tx * 4);
      #pragma unroll
      for (int j = 0; j < 4; ++j){
        acc[0][j] = fmaf(a0, w.f[j], acc[0][j]);
        acc[1][j] = fmaf(a1, w.f[j], acc[1][j]);
      }
    }
    __syncthreads();
  }
  // stage acc into wl (free after last sync) as [w][r] for transposed write
  float* tile = wl;
  #pragma unroll
  for (int i = 0; i < 2; ++i)
    #pragma unroll
    for (int j = 0; j < 4; ++j)
      tile[(tx*4 + j) * 17 + ty*2 + i] = acc[i][j];
  // register-only work while tile settles: lin + bf16 features
  F4 wo; wo.v = *(const float4*)(wout + tx * 4);
  F4 wiv;
  if (MODE == 0) wiv.v = *(const float4*)(wint + tx * 4);
  #pragma unroll
  for (int i = 0; i < 2; ++i){
    int r = rowBase + ty * 2 + i;
    float s = acc[i][0]*wo.f[0] + acc[i][1]*wo.f[1] + acc[i][2]*wo.f[2] + acc[i][3]*wo.f[3];
    #pragma unroll
    for (int off = 16; off >= 1; off >>= 1) s += __shfl_xor(s, off, 32);
    if (tx == 0) lin[r] = s;
    ushort4 g[5];
    uint16_t* gp = (uint16_t*)g;
    #pragma unroll
    for (int j = 0; j < 4; ++j){
      float p = acc[i][j];
      float p2 = p*p, p4 = p2*p2, p6 = p4*p2, p8 = p4*p4;
      float e0, e1, e2, e3, e4;
      if (MODE == 0){
        float wq = wiv.f[j];
        e0 = 0.5f * wq * p; e1 = A1C * wq * p2; e2 = A2C * wq * p4;
        e3 = A3C * wq * p6; e4 = A4C * wq * p8;
      } else {
        e0 = p; e1 = p2; e2 = p4; e3 = p6; e4 = p8;
      }
      gp[0*4+j] = f2bf(e0); gp[1*4+j] = f2bf(e1); gp[2*4+j] = f2bf(e2);
      gp[3*4+j] = f2bf(e3); gp[4*4+j] = f2bf(e4);
    }
    uint16_t* o = feat + (size_t)r * 640 + tx * 4;
    *(ushort4*)(o)       = g[0];
    *(ushort4*)(o + 128) = g[1];
    *(ushort4*)(o + 256) = g[2];
    *(ushort4*)(o + 384) = g[3];
    *(ushort4*)(o + 512) = g[4];
  }
  __syncthreads();
  int b = rowBase >> 12;
  // transposed write: pT[(b*W + w)][s]; scalar LDS reads (stride-17 rows are
  // only 4B-aligned — a float4 LDS read here would be misaligned UB)
  {
    int w = tid >> 1, h = tid & 1;
    int sb = rowBase & (S_ - 1);
    float* dst = pT + ((size_t)(b * W_ + w)) * S_ + sb + h * 8;
    const float* src = tile + w * 17 + h * 8;
    #pragma unroll
    for (int k = 0; k < 2; ++k){
      float4 o = make_float4(src[k*4+0], src[k*4+1], src[k*4+2], src[k*4+3]);
      *(float4*)(dst + k * 4) = o;
    }
  }
  // fused per-(b,w) running max |pt| (fp32 bits monotone for non-negatives)
  if (MODE == 1 && tid < W_){
    int w = tid;
    float m = 0.f;
    #pragma unroll
    for (int r = 0; r < 16; ++r) m = fmaxf(m, fabsf(tile[w * 17 + r]));
    atomicMax((unsigned int*)&maxT[b * W_ + w], __float_as_uint(m));
  }
}

// ---- main GEMM: 256x256 tile, 8 waves (2M x 4N), 8-phase schedule -------
// m201-template port: BK=32, 4 rotating LDS buffers (depth-2 pipeline),
// 4 phases/K-tile: {ds_read frags || 1 gl_lds of tile t+2 -> barrier ->
// setprio(1) -> 8 MFMA -> setprio(0) -> barrier}.  Counted vmcnt(4) once
// per K-tile (never 0 until the tail).  LDS swizzle: content(row,slot) =
// global chunk slot^((row>>1)&3), via pre-swizzled source (rule #21).
template<int OUTBF>
__global__ __launch_bounds__(512) void gemm_k(const uint16_t* __restrict__ fA,
      const uint16_t* __restrict__ fB, const float* __restrict__ slin,
      const float* __restrict__ tlin, const float* __restrict__ cbias,
      void* __restrict__ outv){
  __shared__ __align__(16) uint16_t As[4][256 * 32];
  __shared__ __align__(16) uint16_t Bs[4][256 * 32];
  int tid = threadIdx.x, lane = tid & 63, wv = tid >> 6;
  int quad = lane >> 4, lr = lane & 15;
  int wm = wv >> 2, wn = wv & 3;                  // 2M x 4N wave grid
  int sl = quad ^ ((lane >> 1) & 3);              // swizzled read slot
  int rowT = blockIdx.y * 256, colT = blockIdx.x * 256;
  int bb = rowT >> 12;

  const uint16_t* aBase = fA + (size_t)rowT * 640;
  const uint16_t* bBase = fB + ((size_t)bb * T_ + colT) * 640;

  int srw = tid >> 2;                              // staging row 0..127
  int k0 = (((tid & 3) ^ ((tid >> 3) & 3))) * 8;   // pre-swizzled src chunk

  f32x4 acc[8][4];
  #pragma unroll
  for (int i = 0; i < 8; ++i)
    #pragma unroll
    for (int j = 0; j < 4; ++j)
      acc[i][j] = (f32x4){0.f, 0.f, 0.f, 0.f};

  auto STAGE = [&](int tile, int p){
    int sb = tile & 3;
    int kc = tile * 32;
    if (p == 0)
      gl_lds16(aBase + (size_t)srw * 640 + kc + k0,         &As[sb][tid * 8]);
    else if (p == 1)
      gl_lds16(aBase + (size_t)(128 + srw) * 640 + kc + k0, &As[sb][4096 + tid * 8]);
    else if (p == 2)
      gl_lds16(bBase + (size_t)srw * 640 + kc + k0,         &Bs[sb][tid * 8]);
    else
      gl_lds16(bBase + (size_t)(128 + srw) * 640 + kc + k0, &Bs[sb][4096 + tid * 8]);
  };

  // prologue: stage tiles 0 and 1 (8 loads); wait tile 0 (leave tile 1 flying)
  #pragma unroll
  for (int p = 0; p < 4; ++p) STAGE(0, p);
  #pragma unroll
  for (int p = 0; p < 4; ++p) STAGE(1, p);
  asm volatile("s_waitcnt vmcnt(4)" ::: "memory");
  __builtin_amdgcn_s_barrier();

  for (int tile = 0; tile < 20; ++tile){
    int buf = tile & 3;
    bf16x8 bfr[4];
    #pragma unroll
    for (int p = 0; p < 4; ++p){
      bf16x8 a0 = *(const bf16x8*)&As[buf][(wm*128 + (2*p)*16   + lr) * 32 + sl * 8];
      bf16x8 a1 = *(const bf16x8*)&As[buf][(wm*128 + (2*p+1)*16 + lr) * 32 + sl * 8];
      if (p == 0){
        #pragma unroll
        for (int nj = 0; nj < 4; ++nj)
          bfr[nj] = *(const bf16x8*)&Bs[buf][(wn*64 + nj*16 + lr) * 32 + sl * 8];
      }
      if (tile + 2 < 20) STAGE(tile + 2, p);
      if (p == 3){
        // retire tile+1's 4 loads before next K-tile; keep tile+2's flying
        if (tile + 2 < 20)   asm volatile("s_waitcnt vmcnt(4)" ::: "memory");
        else if (tile < 19)  asm volatile("s_waitcnt vmcnt(0)" ::: "memory");
      }
      __builtin_amdgcn_s_barrier();
      __builtin_amdgcn_s_setprio(1);
      #pragma unroll
      for (int nj = 0; nj < 4; ++nj){
        acc[2*p][nj]   = __builtin_amdgcn_mfma_f32_16x16x32_bf16(bfr[nj], a0, acc[2*p][nj],   0, 0, 0);
        acc[2*p+1][nj] = __builtin_amdgcn_mfma_f32_16x16x32_bf16(bfr[nj], a1, acc[2*p+1][nj], 0, 0, 0);
      }
      __builtin_amdgcn_s_setprio(0);
      __builtin_amdgcn_s_barrier();
    }
  }

  float cb = cbias[0];
  #pragma unroll
  for (int mi = 0; mi < 8; ++mi){
    int srow = rowT + wm * 128 + mi * 16 + lr;
    float sv = slin[srow] + cb;
    #pragma unroll
    for (int nj = 0; nj < 4; ++nj){
      int t0 = colT + wn * 64 + nj * 16 + quad * 4;
      F4 tl; tl.v = *(const float4*)(tlin + bb * T_ + t0);
      float o0 = acc[mi][nj][0] + sv + tl.f[0];
      float o1 = acc[mi][nj][1] + sv + tl.f[1];
      float o2 = acc[mi][nj][2] + sv + tl.f[2];
      float o3 = acc[mi][nj][3] + sv + tl.f[3];
      size_t oi = (size_t)srow * T_ + t0;
      if (OUTBF){
        ushort4 pk = make_ushort4(f2bf(o0), f2bf(o1), f2bf(o2), f2bf(o3));
        *(ushort4*)((uint16_t*)outv + oi) = pk;
      } else {
        *(float4*)((float*)outv + oi) = make_float4(o0, o1, o2, o3);
      }
    }
  }
}

// ---- phase 1: flag rows where |ps|*maxT > ZCUT (coalesced, parallel) ----
__global__ void flagrows_k(const float* __restrict__ psT, const float* __restrict__ maxT,
                           uint32_t* __restrict__ rowList, int* __restrict__ rowCnt){
  int w = blockIdx.x, b = blockIdx.y;
  int tid = threadIdx.x;
  float mt = maxT[b * W_ + w];
  const float* psc = psT + (size_t)(b * W_ + w) * S_;
  for (int s = tid; s < S_; s += 256){
    float p = psc[s];
    if (fabsf(p) * mt > ZCUT){
      int k = atomicAdd(rowCnt, 1);
      if (k < ROWCAP)
        rowList[k] = ((uint32_t)b << 19) | ((uint32_t)w << 12) | (uint32_t)s;
    }
  }
}

// ---- phase 2: grid-stride over flagged rows (load-balanced); exact fix
//      merged into d_out ------------------------------------------------
template<int OUTBF>
__global__ __launch_bounds__(256) void fixscan_k(const float* __restrict__ psT,
        const float* __restrict__ ptT, const float* __restrict__ wint,
        const uint16_t* __restrict__ fA, const uint16_t* __restrict__ fB,
        const uint32_t* __restrict__ rowList, const int* __restrict__ rowCnt,
        void* __restrict__ outv){
  int n = *rowCnt; if (n > ROWCAP) n = ROWCAP;
  int tid = threadIdx.x;
  for (int job = blockIdx.x; job < n; job += gridDim.x){
    uint32_t pk = rowList[job];
    int b = (int)(pk >> 19), w = (int)((pk >> 12) & 127u), s = (int)(pk & 4095u);
    float wi = wint[w];
    float p = psT[(size_t)(b * W_ + w) * S_ + s];
    const float* ptc = ptT + (size_t)(b * W_ + w) * T_;
    const uint16_t* fa = fA + ((size_t)b * S_ + s) * 640 + w;
    float a0 = bf2f(fa[0]),   a1 = bf2f(fa[128]), a2 = bf2f(fa[256]);
    float a3 = bf2f(fa[384]), a4 = bf2f(fa[512]);
    for (int t = tid; t < T_; t += 256){
      float q = ptc[t];
      float z = p * q;
      if (fabsf(z) > ZCUT){
        const uint16_t* fb = fB + ((size_t)b * T_ + t) * 640 + w;
        float dot = a0 * bf2f(fb[0]) + a1 * bf2f(fb[128]) + a2 * bf2f(fb[256])
                  + a3 * bf2f(fb[384]) + a4 * bf2f(fb[512]);
        float sil = z / (1.0f + __expf(-z));
        float corr = wi * sil - dot - A0C * wi;
        size_t idx = ((size_t)b * S_ + s) * T_ + t;
        if (OUTBF){
          uint32_t* wp = (uint32_t*)outv + (idx >> 1);
          bool hi = (idx & 1u) != 0;
          uint32_t assumed, old = *wp;
          do {
            assumed = old;
            uint16_t h = hi ? (uint16_t)(assumed >> 16) : (uint16_t)(assumed & 0xFFFFu);
            uint16_t nh = f2bf(bf2f(h) + corr);
            uint32_t nw = hi ? ((assumed & 0x0000FFFFu) | ((uint32_t)nh << 16))
                             : ((assumed & 0xFFFF0000u) | (uint32_t)nh);
            old = atomicCAS(wp, assumed, nw);
          } while (old != assumed);
        } else {
          atomicAdd((float*)outv + idx, corr);
        }
      }
    }
  }
}

extern "C" void kernel_launch(void* const* d_in, const int* in_sizes, int n_in,
                              void* d_out, int out_size, void* d_ws, size_t ws_size,
                              hipStream_t stream){
  char* ws = (char*)d_ws;
  size_t off = 0;
  auto alloc = [&](size_t bytes)->char*{
    char* p = ws + off; off += (bytes + 255) & ~(size_t)255; return p;
  };
  float*    WsT  = (float*)   alloc((size_t)D_*W_*4);
  float*    WtT  = (float*)   alloc((size_t)D_*W_*4);
  float*    wsof = (float*)   alloc(W_*4);
  float*    wtof = (float*)   alloc(W_*4);
  float*    wif  = (float*)   alloc(W_*4);
  float*    cbias= (float*)   alloc(4);
  int*      rowCnt=(int*)     alloc(4);
  uint32_t* rowList=(uint32_t*)alloc((size_t)ROWCAP*4);
  float*    psT  = (float*)   alloc((size_t)B_*S_*W_*4);
  float*    ptT  = (float*)   alloc((size_t)B_*T_*W_*4);
  float*    slin = (float*)   alloc((size_t)B_*S_*4);
  float*    tlin = (float*)   alloc((size_t)B_*T_*4);
  float*    maxT = (float*)   alloc((size_t)B_*W_*4);
  uint16_t* featA= (uint16_t*)alloc((size_t)B_*S_*640*2);
  uint16_t* featB= (uint16_t*)alloc((size_t)B_*T_*640*2);

  // host-side dtype dispatch from byte sizes (fp32 if ambiguous)
  bool inbf  = (in_sizes[0] == (int)((size_t)B_*S_*D_*2));
  bool outbf = (out_size    == (int)((size_t)B_*S_*T_*2));

  if (inbf){
    hipLaunchKernelGGL((prep_k<1>), dim3(32), dim3(256), 0, stream,
        d_in[2], d_in[3], d_in[4], d_in[5], d_in[6], d_in[7],
        WsT, WtT, wsof, wtof, wif, cbias, maxT, rowCnt);
    hipLaunchKernelGGL((proj_k<1,0>), dim3(B_*S_/16), dim3(256), 0, stream,
        d_in[0], WsT, wsof, wif, psT, slin, featA, maxT);
    hipLaunchKernelGGL((proj_k<1,1>), dim3(B_*T_/16), dim3(256), 0, stream,
        d_in[1], WtT, wtof, wif, ptT, tlin, featB, maxT);
  } else {
    hipLaunchKernelGGL((prep_k<0>), dim3(32), dim3(256), 0, stream,
        d_in[2], d_in[3], d_in[4], d_in[5], d_in[6], d_in[7],
        WsT, WtT, wsof, wtof, wif, cbias, maxT, rowCnt);
    hipLaunchKernelGGL((proj_k<0,0>), dim3(B_*S_/16), dim3(256), 0, stream,
        d_in[0], WsT, wsof, wif, psT, slin, featA, maxT);
    hipLaunchKernelGGL((proj_k<0,1>), dim3(B_*T_/16), dim3(256), 0, stream,
        d_in[1], WtT, wtof, wif, ptT, tlin, featB, maxT);
  }
  if (outbf)
    hipLaunchKernelGGL((gemm_k<1>), dim3(T_/256, B_*S_/256), dim3(512), 0, stream,
        featA, featB, slin, tlin, cbias, d_out);
  else
    hipLaunchKernelGGL((gemm_k<0>), dim3(T_/256, B_*S_/256), dim3(512), 0, stream,
        featA, featB, slin, tlin, cbias, d_out);
  hipLaunchKernelGGL(flagrows_k, dim3(W_, B_), dim3(256), 0, stream,
      psT, maxT, rowList, rowCnt);
  if (outbf)
    hipLaunchKernelGGL((fixscan_k<1>), dim3(2048), dim3(256), 0, stream,
        psT, ptT, wif, featA, featB, rowList, rowCnt, d_out);
  else
    hipLaunchKernelGGL((fixscan_k<0>), dim3(2048), dim3(256), 0, stream,
        psT, ptT, wif, featA, featB, rowList, rowCnt, d_out);
}

// Round 9
// 308.401 us; speedup vs baseline: 1.0172x; 1.0172x over previous
//
#include <hip/hip_runtime.h>
#include <cstdint>
#include <cstddef>

#define B_ 2
#define S_ 4096
#define T_ 4096
#define D_ 512
#define W_ 128

// degree-4 poly in t=z^2 for h(t) = silu(z) - z/2, fit on t in [0, 6.25]
#define A0C (-0.0006958f)
#define A1C (0.2529946f)
#define A2C (-0.0226345f)
#define A3C (0.0022173f)
#define A4C (-0.00011668f)
#define ZCUT 2.5f
#define ROWCAP 65536

typedef __attribute__((ext_vector_type(8))) short bf16x8;
typedef __attribute__((ext_vector_type(4))) float f32x4;

__device__ __forceinline__ uint16_t f2bf(float f){
  uint32_t u = __float_as_uint(f);
  u += 0x7FFFu + ((u >> 16) & 1u);        // round-to-nearest-even
  return (uint16_t)(u >> 16);
}
__device__ __forceinline__ float bf2f(uint16_t h){
  return __uint_as_float(((uint32_t)h) << 16);
}

__device__ __forceinline__ void gl_lds16(const void* g, void* l){
  __builtin_amdgcn_global_load_lds(
      (const __attribute__((address_space(1))) void*)g,
      (__attribute__((address_space(3))) void*)l, 16, 0, 0);
}

union F4 { float4 v; float f[4]; };

// ---- prep: transpose weights (coalesced WRITES, scattered L2 reads),
//      convert small vecs, cbias, zero maxT + rowCnt.  32 blocks.
template<int INBF>
__global__ void prep_k(const void* __restrict__ Ws, const void* __restrict__ Wt,
                       const void* __restrict__ wso, const void* __restrict__ wto,
                       const void* __restrict__ wi, const void* __restrict__ bias,
                       float* __restrict__ WsT, float* __restrict__ WtT,
                       float* __restrict__ wsof, float* __restrict__ wtof,
                       float* __restrict__ wif, float* __restrict__ cbias,
                       float* __restrict__ maxT, int* __restrict__ rowCnt){
  auto cv = [](const void* p, int i)->float{
    if (INBF) return bf2f(((const uint16_t*)p)[i]);
    return ((const float*)p)[i];
  };
  const void* in = (blockIdx.x & 1) ? Wt : Ws;
  float* out = (blockIdx.x & 1) ? WtT : WsT;
  int base = (blockIdx.x >> 1) * 4096;
  for (int o = base + threadIdx.x; o < base + 4096; o += blockDim.x){
    int d = o >> 7, w = o & (W_ - 1);
    out[o] = cv(in, w * D_ + d);          // write linear/coalesced
  }
  if (blockIdx.x == 1){
    maxT[threadIdx.x] = 0.f;              // B_*W_ = 256 entries
  }
  if (blockIdx.x == 0){
    if (threadIdx.x < W_){
      wsof[threadIdx.x] = cv(wso, threadIdx.x);
      wtof[threadIdx.x] = cv(wto, threadIdx.x);
      wif[threadIdx.x]  = cv(wi,  threadIdx.x);
    }
    __syncthreads();
    if (threadIdx.x == 0){
      float s = 0.f;
      for (int k = 0; k < W_; ++k) s += wif[k];
      cbias[0] = cv(bias, 0) + A0C * s;
      rowCnt[0] = 0;
    }
  }
}

// ---- fused projection: raw input -> pT (transposed), lin, bf16 features
// 16 rows/block (512 blocks, 2 waves/SIMD).  MODE 0 = source (features
// scaled by w_int + poly coeffs), MODE 1 = target (+ fused maxT atomicMax)
template<int INBF, int MODE>
__global__ __launch_bounds__(256) void proj_k(const void* __restrict__ xraw,
        const float* __restrict__ WT, const float* __restrict__ wout,
        const float* __restrict__ wint,
        float* __restrict__ pT, float* __restrict__ lin,
        uint16_t* __restrict__ feat, float* __restrict__ maxT){
  __shared__ float xl[64 * 18];
  __shared__ float wl[64 * 128];
  int tid = threadIdx.x;
  int tx = tid & 31, ty = tid >> 5;
  int rowBase = blockIdx.x * 16;
  float acc[2][4] = {};
  for (int c = 0; c < 8; ++c){
    int d0 = c * 64;
    const float4* wt4 = (const float4*)(WT + (size_t)d0 * W_);
    float4* wl4 = (float4*)wl;
    #pragma unroll
    for (int p = 0; p < 8; ++p){ int q = tid + 256 * p; wl4[q] = wt4[q]; }
    {
      int q = tid;
      int r = q >> 4, dq = q & 15;
      float v0, v1, v2, v3;
      if (INBF){
        const uint16_t* xp = (const uint16_t*)xraw + (size_t)(rowBase + r) * D_ + d0 + dq * 4;
        ushort4 u = *(const ushort4*)xp;
        v0 = bf2f(u.x); v1 = bf2f(u.y); v2 = bf2f(u.z); v3 = bf2f(u.w);
      } else {
        const float* xp = (const float*)xraw + (size_t)(rowBase + r) * D_ + d0 + dq * 4;
        float4 u = *(const float4*)xp;
        v0 = u.x; v1 = u.y; v2 = u.z; v3 = u.w;
      }
      xl[(dq*4+0)*18 + r] = v0;
      xl[(dq*4+1)*18 + r] = v1;
      xl[(dq*4+2)*18 + r] = v2;
      xl[(dq*4+3)*18 + r] = v3;
    }
    __syncthreads();
    #pragma unroll 4
    for (int d = 0; d < 64; ++d){
      float a0 = xl[d * 18 + ty * 2 + 0];
      float a1 = xl[d * 18 + ty * 2 + 1];
      F4 w;
      w.v = *(const float4*)(wl + d * 128 + tx * 4);
      #pragma unroll
      for (int j = 0; j < 4; ++j){
        acc[0][j] = fmaf(a0, w.f[j], acc[0][j]);
        acc[1][j] = fmaf(a1, w.f[j], acc[1][j]);
      }
    }
    __syncthreads();
  }
  // stage acc into wl (free after last sync) as [w][r] for transposed write
  float* tile = wl;
  #pragma unroll
  for (int i = 0; i < 2; ++i)
    #pragma unroll
    for (int j = 0; j < 4; ++j)
      tile[(tx*4 + j) * 17 + ty*2 + i] = acc[i][j];
  // register-only work while tile settles: lin + bf16 features
  F4 wo; wo.v = *(const float4*)(wout + tx * 4);
  F4 wiv;
  if (MODE == 0) wiv.v = *(const float4*)(wint + tx * 4);
  #pragma unroll
  for (int i = 0; i < 2; ++i){
    int r = rowBase + ty * 2 + i;
    float s = acc[i][0]*wo.f[0] + acc[i][1]*wo.f[1] + acc[i][2]*wo.f[2] + acc[i][3]*wo.f[3];
    #pragma unroll
    for (int off = 16; off >= 1; off >>= 1) s += __shfl_xor(s, off, 32);
    if (tx == 0) lin[r] = s;
    ushort4 g[5];
    uint16_t* gp = (uint16_t*)g;
    #pragma unroll
    for (int j = 0; j < 4; ++j){
      float p = acc[i][j];
      float p2 = p*p, p4 = p2*p2, p6 = p4*p2, p8 = p4*p4;
      float e0, e1, e2, e3, e4;
      if (MODE == 0){
        float wq = wiv.f[j];
        e0 = 0.5f * wq * p; e1 = A1C * wq * p2; e2 = A2C * wq * p4;
        e3 = A3C * wq * p6; e4 = A4C * wq * p8;
      } else {
        e0 = p; e1 = p2; e2 = p4; e3 = p6; e4 = p8;
      }
      gp[0*4+j] = f2bf(e0); gp[1*4+j] = f2bf(e1); gp[2*4+j] = f2bf(e2);
      gp[3*4+j] = f2bf(e3); gp[4*4+j] = f2bf(e4);
    }
    uint16_t* o = feat + (size_t)r * 640 + tx * 4;
    *(ushort4*)(o)       = g[0];
    *(ushort4*)(o + 128) = g[1];
    *(ushort4*)(o + 256) = g[2];
    *(ushort4*)(o + 384) = g[3];
    *(ushort4*)(o + 512) = g[4];
  }
  __syncthreads();
  int b = rowBase >> 12;
  // transposed write: pT[(b*W + w)][s]; scalar LDS reads (stride-17 rows are
  // only 4B-aligned — a float4 LDS read here would be misaligned UB)
  {
    int w = tid >> 1, h = tid & 1;
    int sb = rowBase & (S_ - 1);
    float* dst = pT + ((size_t)(b * W_ + w)) * S_ + sb + h * 8;
    const float* src = tile + w * 17 + h * 8;
    #pragma unroll
    for (int k = 0; k < 2; ++k){
      float4 o = make_float4(src[k*4+0], src[k*4+1], src[k*4+2], src[k*4+3]);
      *(float4*)(dst + k * 4) = o;
    }
  }
  // fused per-(b,w) running max |pt| (fp32 bits monotone for non-negatives)
  if (MODE == 1 && tid < W_){
    int w = tid;
    float m = 0.f;
    #pragma unroll
    for (int r = 0; r < 16; ++r) m = fmaxf(m, fabsf(tile[w * 17 + r]));
    atomicMax((unsigned int*)&maxT[b * W_ + w], __float_as_uint(m));
  }
}

// ---- main GEMM: 256x256 tile, 8 waves (2M x 4N), coarse schedule --------
// Round-7-proven loop at 256² scale: per K-tile(32) ONE barrier pair, 32
// MFMA/wave window, counted vmcnt(4) depth-1 prefetch (never drains), 2 LDS
// buffers (64 KB).  Swizzle (rule #21 both-sides): LDS slot content(r,c) =
// global chunk c^((r>>1)&3) via pre-swizzled source; read slot =
// quad^((lane>>1)&3) -> (r&1,slot) covers all 8 bank-groups, 2 lanes each.
template<int OUTBF>
__global__ __launch_bounds__(512) void gemm_k(const uint16_t* __restrict__ fA,
      const uint16_t* __restrict__ fB, const float* __restrict__ slin,
      const float* __restrict__ tlin, const float* __restrict__ cbias,
      void* __restrict__ outv){
  __shared__ __align__(16) uint16_t As[2][256 * 32];
  __shared__ __align__(16) uint16_t Bs[2][256 * 32];
  int tid = threadIdx.x, lane = tid & 63, wv = tid >> 6;
  int quad = lane >> 4, lr = lane & 15;
  int wm = wv >> 2, wn = wv & 3;                  // 2M x 4N wave grid
  int sl = quad ^ ((lane >> 1) & 3);              // swizzled read slot
  int rowT = blockIdx.y * 256, colT = blockIdx.x * 256;
  int bb = rowT >> 12;

  const uint16_t* aBase = fA + (size_t)rowT * 640;
  const uint16_t* bBase = fB + ((size_t)bb * T_ + colT) * 640;

  int srw = tid >> 2;                              // staging row 0..127
  int k0 = (((tid & 3) ^ ((tid >> 3) & 3))) * 8;   // pre-swizzled src chunk

  f32x4 acc[8][4];
  #pragma unroll
  for (int i = 0; i < 8; ++i)
    #pragma unroll
    for (int j = 0; j < 4; ++j)
      acc[i][j] = (f32x4){0.f, 0.f, 0.f, 0.f};

  auto STAGE = [&](int tile){
    int sb = tile & 1;
    int kc = tile * 32;
    gl_lds16(aBase + (size_t)srw * 640 + kc + k0,         &As[sb][tid * 8]);
    gl_lds16(aBase + (size_t)(128 + srw) * 640 + kc + k0, &As[sb][4096 + tid * 8]);
    gl_lds16(bBase + (size_t)srw * 640 + kc + k0,         &Bs[sb][tid * 8]);
    gl_lds16(bBase + (size_t)(128 + srw) * 640 + kc + k0, &Bs[sb][4096 + tid * 8]);
  };

  // prologue: stage tile 0 into buffer 0
  STAGE(0);
  for (int tile = 0; tile < 20; ++tile){
    int buf = tile & 1;
    if (tile + 1 < 20){
      STAGE(tile + 1);
      // retire tile's 4 loads (oldest); keep tile+1's 4 in flight
      asm volatile("s_waitcnt vmcnt(4)" ::: "memory");
    } else {
      asm volatile("s_waitcnt vmcnt(0)" ::: "memory");
    }
    __builtin_amdgcn_s_barrier();
    bf16x8 bq[4];
    #pragma unroll
    for (int nj = 0; nj < 4; ++nj)
      bq[nj] = *(const bf16x8*)&Bs[buf][(wn*64 + nj*16 + lr) * 32 + sl * 8];
    #pragma unroll
    for (int mi = 0; mi < 8; ++mi){
      bf16x8 aq = *(const bf16x8*)&As[buf][(wm*128 + mi*16 + lr) * 32 + sl * 8];
      #pragma unroll
      for (int nj = 0; nj < 4; ++nj)
        acc[mi][nj] = __builtin_amdgcn_mfma_f32_16x16x32_bf16(bq[nj], aq, acc[mi][nj], 0, 0, 0);
    }
    __builtin_amdgcn_s_barrier();
  }

  float cb = cbias[0];
  #pragma unroll
  for (int mi = 0; mi < 8; ++mi){
    int srow = rowT + wm * 128 + mi * 16 + lr;
    float sv = slin[srow] + cb;
    #pragma unroll
    for (int nj = 0; nj < 4; ++nj){
      int t0 = colT + wn * 64 + nj * 16 + quad * 4;
      F4 tl; tl.v = *(const float4*)(tlin + bb * T_ + t0);
      float o0 = acc[mi][nj][0] + sv + tl.f[0];
      float o1 = acc[mi][nj][1] + sv + tl.f[1];
      float o2 = acc[mi][nj][2] + sv + tl.f[2];
      float o3 = acc[mi][nj][3] + sv + tl.f[3];
      size_t oi = (size_t)srow * T_ + t0;
      if (OUTBF){
        ushort4 pk = make_ushort4(f2bf(o0), f2bf(o1), f2bf(o2), f2bf(o3));
        *(ushort4*)((uint16_t*)outv + oi) = pk;
      } else {
        *(float4*)((float*)outv + oi) = make_float4(o0, o1, o2, o3);
      }
    }
  }
}

// ---- phase 1: flag rows where |ps|*maxT > ZCUT (coalesced, parallel) ----
__global__ void flagrows_k(const float* __restrict__ psT, const float* __restrict__ maxT,
                           uint32_t* __restrict__ rowList, int* __restrict__ rowCnt){
  int w = blockIdx.x, b = blockIdx.y;
  int tid = threadIdx.x;
  float mt = maxT[b * W_ + w];
  const float* psc = psT + (size_t)(b * W_ + w) * S_;
  for (int s = tid; s < S_; s += 256){
    float p = psc[s];
    if (fabsf(p) * mt > ZCUT){
      int k = atomicAdd(rowCnt, 1);
      if (k < ROWCAP)
        rowList[k] = ((uint32_t)b << 19) | ((uint32_t)w << 12) | (uint32_t)s;
    }
  }
}

// ---- phase 2: grid-stride over flagged rows (load-balanced); exact fix
//      merged into d_out ------------------------------------------------
template<int OUTBF>
__global__ __launch_bounds__(256) void fixscan_k(const float* __restrict__ psT,
        const float* __restrict__ ptT, const float* __restrict__ wint,
        const uint16_t* __restrict__ fA, const uint16_t* __restrict__ fB,
        const uint32_t* __restrict__ rowList, const int* __restrict__ rowCnt,
        void* __restrict__ outv){
  int n = *rowCnt; if (n > ROWCAP) n = ROWCAP;
  int tid = threadIdx.x;
  for (int job = blockIdx.x; job < n; job += gridDim.x){
    uint32_t pk = rowList[job];
    int b = (int)(pk >> 19), w = (int)((pk >> 12) & 127u), s = (int)(pk & 4095u);
    float wi = wint[w];
    float p = psT[(size_t)(b * W_ + w) * S_ + s];
    const float* ptc = ptT + (size_t)(b * W_ + w) * T_;
    const uint16_t* fa = fA + ((size_t)b * S_ + s) * 640 + w;
    float a0 = bf2f(fa[0]),   a1 = bf2f(fa[128]), a2 = bf2f(fa[256]);
    float a3 = bf2f(fa[384]), a4 = bf2f(fa[512]);
    for (int t = tid; t < T_; t += 256){
      float q = ptc[t];
      float z = p * q;
      if (fabsf(z) > ZCUT){
        const uint16_t* fb = fB + ((size_t)b * T_ + t) * 640 + w;
        float dot = a0 * bf2f(fb[0]) + a1 * bf2f(fb[128]) + a2 * bf2f(fb[256])
                  + a3 * bf2f(fb[384]) + a4 * bf2f(fb[512]);
        float sil = z / (1.0f + __expf(-z));
        float corr = wi * sil - dot - A0C * wi;
        size_t idx = ((size_t)b * S_ + s) * T_ + t;
        if (OUTBF){
          uint32_t* wp = (uint32_t*)outv + (idx >> 1);
          bool hi = (idx & 1u) != 0;
          uint32_t assumed, old = *wp;
          do {
            assumed = old;
            uint16_t h = hi ? (uint16_t)(assumed >> 16) : (uint16_t)(assumed & 0xFFFFu);
            uint16_t nh = f2bf(bf2f(h) + corr);
            uint32_t nw = hi ? ((assumed & 0x0000FFFFu) | ((uint32_t)nh << 16))
                             : ((assumed & 0xFFFF0000u) | (uint32_t)nh);
            old = atomicCAS(wp, assumed, nw);
          } while (old != assumed);
        } else {
          atomicAdd((float*)outv + idx, corr);
        }
      }
    }
  }
}

extern "C" void kernel_launch(void* const* d_in, const int* in_sizes, int n_in,
                              void* d_out, int out_size, void* d_ws, size_t ws_size,
                              hipStream_t stream){
  char* ws = (char*)d_ws;
  size_t off = 0;
  auto alloc = [&](size_t bytes)->char*{
    char* p = ws + off; off += (bytes + 255) & ~(size_t)255; return p;
  };
  float*    WsT  = (float*)   alloc((size_t)D_*W_*4);
  float*    WtT  = (float*)   alloc((size_t)D_*W_*4);
  float*    wsof = (float*)   alloc(W_*4);
  float*    wtof = (float*)   alloc(W_*4);
  float*    wif  = (float*)   alloc(W_*4);
  float*    cbias= (float*)   alloc(4);
  int*      rowCnt=(int*)     alloc(4);
  uint32_t* rowList=(uint32_t*)alloc((size_t)ROWCAP*4);
  float*    psT  = (float*)   alloc((size_t)B_*S_*W_*4);
  float*    ptT  = (float*)   alloc((size_t)B_*T_*W_*4);
  float*    slin = (float*)   alloc((size_t)B_*S_*4);
  float*    tlin = (float*)   alloc((size_t)B_*T_*4);
  float*    maxT = (float*)   alloc((size_t)B_*W_*4);
  uint16_t* featA= (uint16_t*)alloc((size_t)B_*S_*640*2);
  uint16_t* featB= (uint16_t*)alloc((size_t)B_*T_*640*2);

  // host-side dtype dispatch from byte sizes (fp32 if ambiguous)
  bool inbf  = (in_sizes[0] == (int)((size_t)B_*S_*D_*2));
  bool outbf = (out_size    == (int)((size_t)B_*S_*T_*2));

  if (inbf){
    hipLaunchKernelGGL((prep_k<1>), dim3(32), dim3(256), 0, stream,
        d_in[2], d_in[3], d_in[4], d_in[5], d_in[6], d_in[7],
        WsT, WtT, wsof, wtof, wif, cbias, maxT, rowCnt);
    hipLaunchKernelGGL((proj_k<1,0>), dim3(B_*S_/16), dim3(256), 0, stream,
        d_in[0], WsT, wsof, wif, psT, slin, featA, maxT);
    hipLaunchKernelGGL((proj_k<1,1>), dim3(B_*T_/16), dim3(256), 0, stream,
        d_in[1], WtT, wtof, wif, ptT, tlin, featB, maxT);
  } else {
    hipLaunchKernelGGL((prep_k<0>), dim3(32), dim3(256), 0, stream,
        d_in[2], d_in[3], d_in[4], d_in[5], d_in[6], d_in[7],
        WsT, WtT, wsof, wtof, wif, cbias, maxT, rowCnt);
    hipLaunchKernelGGL((proj_k<0,0>), dim3(B_*S_/16), dim3(256), 0, stream,
        d_in[0], WsT, wsof, wif, psT, slin, featA, maxT);
    hipLaunchKernelGGL((proj_k<0,1>), dim3(B_*T_/16), dim3(256), 0, stream,
        d_in[1], WtT, wtof, wif, ptT, tlin, featB, maxT);
  }
  if (outbf)
    hipLaunchKernelGGL((gemm_k<1>), dim3(T_/256, B_*S_/256), dim3(512), 0, stream,
        featA, featB, slin, tlin, cbias, d_out);
  else
    hipLaunchKernelGGL((gemm_k<0>), dim3(T_/256, B_*S_/256), dim3(512), 0, stream,
        featA, featB, slin, tlin, cbias, d_out);
  hipLaunchKernelGGL(flagrows_k, dim3(W_, B_), dim3(256), 0, stream,
      psT, maxT, rowList, rowCnt);
  if (outbf)
    hipLaunchKernelGGL((fixscan_k<1>), dim3(2048), dim3(256), 0, stream,
        psT, ptT, wif, featA, featB, rowList, rowCnt, d_out);
  else
    hipLaunchKernelGGL((fixscan_k<0>), dim3(2048), dim3(256), 0, stream,
        psT, ptT, wif, featA, featB, rowList, rowCnt, d_out);
}

// Round 10
// 300.949 us; speedup vs baseline: 1.0424x; 1.0248x over previous
//
#include <hip/hip_runtime.h>
#include <cstdint>
#include <cstddef>

#define B_ 2
#define S_ 4096
#define T_ 4096
#define D_ 512
#define W_ 128

// degree-4 poly in t=z^2 for h(t) = silu(z) - z/2, fit on t in [0, 6.25]
#define A0C (-0.0006958f)
#define A1C (0.2529946f)
#define A2C (-0.0226345f)
#define A3C (0.0022173f)
#define A4C (-0.00011668f)
#define ZCUT 2.5f
#define ROWCAP 65536

typedef __attribute__((ext_vector_type(8))) short bf16x8;
typedef __attribute__((ext_vector_type(4))) float f32x4;

__device__ __forceinline__ uint16_t f2bf(float f){
  uint32_t u = __float_as_uint(f);
  u += 0x7FFFu + ((u >> 16) & 1u);        // round-to-nearest-even
  return (uint16_t)(u >> 16);
}
__device__ __forceinline__ float bf2f(uint16_t h){
  return __uint_as_float(((uint32_t)h) << 16);
}

__device__ __forceinline__ void gl_lds16(const void* g, void* l){
  __builtin_amdgcn_global_load_lds(
      (const __attribute__((address_space(1))) void*)g,
      (__attribute__((address_space(3))) void*)l, 16, 0, 0);
}

union F4 { float4 v; float f[4]; };

// ---- prep: transpose weights (coalesced WRITES, scattered L2 reads),
//      convert small vecs, cbias, zero maxT + rowCnt.  32 blocks.
template<int INBF>
__global__ void prep_k(const void* __restrict__ Ws, const void* __restrict__ Wt,
                       const void* __restrict__ wso, const void* __restrict__ wto,
                       const void* __restrict__ wi, const void* __restrict__ bias,
                       float* __restrict__ WsT, float* __restrict__ WtT,
                       float* __restrict__ wsof, float* __restrict__ wtof,
                       float* __restrict__ wif, float* __restrict__ cbias,
                       float* __restrict__ maxT, int* __restrict__ rowCnt){
  auto cv = [](const void* p, int i)->float{
    if (INBF) return bf2f(((const uint16_t*)p)[i]);
    return ((const float*)p)[i];
  };
  const void* in = (blockIdx.x & 1) ? Wt : Ws;
  float* out = (blockIdx.x & 1) ? WtT : WsT;
  int base = (blockIdx.x >> 1) * 4096;
  for (int o = base + threadIdx.x; o < base + 4096; o += blockDim.x){
    int d = o >> 7, w = o & (W_ - 1);
    out[o] = cv(in, w * D_ + d);          // write linear/coalesced
  }
  if (blockIdx.x == 1){
    maxT[threadIdx.x] = 0.f;              // B_*W_ = 256 entries
  }
  if (blockIdx.x == 0){
    if (threadIdx.x < W_){
      wsof[threadIdx.x] = cv(wso, threadIdx.x);
      wtof[threadIdx.x] = cv(wto, threadIdx.x);
      wif[threadIdx.x]  = cv(wi,  threadIdx.x);
    }
    __syncthreads();
    if (threadIdx.x == 0){
      float s = 0.f;
      for (int k = 0; k < W_; ++k) s += wif[k];
      cbias[0] = cv(bias, 0) + A0C * s;
      rowCnt[0] = 0;
    }
  }
}

// ---- fused projection (MERGED src+tgt): 16 rows/block, 1024 blocks.
// blocks [0,512) = source (features scaled by w_int + poly coeffs),
// blocks [512,1024) = target (+ fused maxT atomicMax).  MODE is a
// block-uniform runtime branch.
template<int INBF>
__global__ __launch_bounds__(256) void proj_k(
        const void* __restrict__ xrawS, const void* __restrict__ xrawT,
        const float* __restrict__ WsT, const float* __restrict__ WtT,
        const float* __restrict__ wsof, const float* __restrict__ wtof,
        const float* __restrict__ wint,
        float* __restrict__ psT, float* __restrict__ ptT,
        float* __restrict__ slin, float* __restrict__ tlin,
        uint16_t* __restrict__ featA, uint16_t* __restrict__ featB,
        float* __restrict__ maxT){
  __shared__ float xl[64 * 18];
  __shared__ float wl[64 * 128];
  int tid = threadIdx.x;
  int tx = tid & 31, ty = tid >> 5;
  int mode = (blockIdx.x >= 512) ? 1 : 0;
  const void* xraw = mode ? xrawT : xrawS;
  const float* WT  = mode ? WtT : WsT;
  const float* wout= mode ? wtof : wsof;
  float* pT        = mode ? ptT : psT;
  float* lin       = mode ? tlin : slin;
  uint16_t* feat   = mode ? featB : featA;
  int rowBase = (blockIdx.x & 511) * 16;
  float acc[2][4] = {};
  for (int c = 0; c < 8; ++c){
    int d0 = c * 64;
    const float4* wt4 = (const float4*)(WT + (size_t)d0 * W_);
    float4* wl4 = (float4*)wl;
    #pragma unroll
    for (int p = 0; p < 8; ++p){ int q = tid + 256 * p; wl4[q] = wt4[q]; }
    {
      int q = tid;
      int r = q >> 4, dq = q & 15;
      float v0, v1, v2, v3;
      if (INBF){
        const uint16_t* xp = (const uint16_t*)xraw + (size_t)(rowBase + r) * D_ + d0 + dq * 4;
        ushort4 u = *(const ushort4*)xp;
        v0 = bf2f(u.x); v1 = bf2f(u.y); v2 = bf2f(u.z); v3 = bf2f(u.w);
      } else {
        const float* xp = (const float*)xraw + (size_t)(rowBase + r) * D_ + d0 + dq * 4;
        float4 u = *(const float4*)xp;
        v0 = u.x; v1 = u.y; v2 = u.z; v3 = u.w;
      }
      xl[(dq*4+0)*18 + r] = v0;
      xl[(dq*4+1)*18 + r] = v1;
      xl[(dq*4+2)*18 + r] = v2;
      xl[(dq*4+3)*18 + r] = v3;
    }
    __syncthreads();
    #pragma unroll 4
    for (int d = 0; d < 64; ++d){
      float a0 = xl[d * 18 + ty * 2 + 0];
      float a1 = xl[d * 18 + ty * 2 + 1];
      F4 w;
      w.v = *(const float4*)(wl + d * 128 + tx * 4);
      #pragma unroll
      for (int j = 0; j < 4; ++j){
        acc[0][j] = fmaf(a0, w.f[j], acc[0][j]);
        acc[1][j] = fmaf(a1, w.f[j], acc[1][j]);
      }
    }
    __syncthreads();
  }
  // stage acc into wl (free after last sync) as [w][r] for transposed write
  float* tile = wl;
  #pragma unroll
  for (int i = 0; i < 2; ++i)
    #pragma unroll
    for (int j = 0; j < 4; ++j)
      tile[(tx*4 + j) * 17 + ty*2 + i] = acc[i][j];
  // register-only work while tile settles: lin + bf16 features
  F4 wo; wo.v = *(const float4*)(wout + tx * 4);
  F4 wiv;
  if (mode == 0) wiv.v = *(const float4*)(wint + tx * 4);
  #pragma unroll
  for (int i = 0; i < 2; ++i){
    int r = rowBase + ty * 2 + i;
    float s = acc[i][0]*wo.f[0] + acc[i][1]*wo.f[1] + acc[i][2]*wo.f[2] + acc[i][3]*wo.f[3];
    #pragma unroll
    for (int off = 16; off >= 1; off >>= 1) s += __shfl_xor(s, off, 32);
    if (tx == 0) lin[r] = s;
    ushort4 g[5];
    uint16_t* gp = (uint16_t*)g;
    #pragma unroll
    for (int j = 0; j < 4; ++j){
      float p = acc[i][j];
      float p2 = p*p, p4 = p2*p2, p6 = p4*p2, p8 = p4*p4;
      float e0, e1, e2, e3, e4;
      if (mode == 0){
        float wq = wiv.f[j];
        e0 = 0.5f * wq * p; e1 = A1C * wq * p2; e2 = A2C * wq * p4;
        e3 = A3C * wq * p6; e4 = A4C * wq * p8;
      } else {
        e0 = p; e1 = p2; e2 = p4; e3 = p6; e4 = p8;
      }
      gp[0*4+j] = f2bf(e0); gp[1*4+j] = f2bf(e1); gp[2*4+j] = f2bf(e2);
      gp[3*4+j] = f2bf(e3); gp[4*4+j] = f2bf(e4);
    }
    uint16_t* o = feat + (size_t)r * 640 + tx * 4;
    *(ushort4*)(o)       = g[0];
    *(ushort4*)(o + 128) = g[1];
    *(ushort4*)(o + 256) = g[2];
    *(ushort4*)(o + 384) = g[3];
    *(ushort4*)(o + 512) = g[4];
  }
  __syncthreads();
  int b = rowBase >> 12;
  // transposed write: pT[(b*W + w)][s]; scalar LDS reads (stride-17 rows are
  // only 4B-aligned — a float4 LDS read here would be misaligned UB)
  {
    int w = tid >> 1, h = tid & 1;
    int sb = rowBase & (S_ - 1);
    float* dst = pT + ((size_t)(b * W_ + w)) * S_ + sb + h * 8;
    const float* src = tile + w * 17 + h * 8;
    #pragma unroll
    for (int k = 0; k < 2; ++k){
      float4 o = make_float4(src[k*4+0], src[k*4+1], src[k*4+2], src[k*4+3]);
      *(float4*)(dst + k * 4) = o;
    }
  }
  // fused per-(b,w) running max |pt| (fp32 bits monotone for non-negatives)
  if (mode == 1 && tid < W_){
    int w = tid;
    float m = 0.f;
    #pragma unroll
    for (int r = 0; r < 16; ++r) m = fmaxf(m, fabsf(tile[w * 17 + r]));
    atomicMax((unsigned int*)&maxT[b * W_ + w], __float_as_uint(m));
  }
}

// ---- main GEMM: 256x256 tile, 8 waves (2M x 4N), coarse schedule --------
// One barrier pair per K-tile(32), 32 MFMA/wave window, counted vmcnt(4)
// depth-1 prefetch, 2 LDS buffers (64 KB, 2 blocks/CU).  Swizzle (rule #21
// both-sides): pre-swizzled global source chunk + XOR'd read slot -> 0
// bank conflicts (verified r8/r9).  NEW: XCD-aware block remap (T1) — each
// XCD owns a contiguous 8x8 tile region so its 64 co-resident blocks share
// 8 A-panels + 8 B-panels (~5.2 MB) instead of ~15.7 MB (L2 = 4 MB/XCD).
template<int OUTBF>
__global__ __launch_bounds__(512) void gemm_k(const uint16_t* __restrict__ fA,
      const uint16_t* __restrict__ fB, const float* __restrict__ slin,
      const float* __restrict__ tlin, const float* __restrict__ cbias,
      void* __restrict__ outv){
  __shared__ __align__(16) uint16_t As[2][256 * 32];
  __shared__ __align__(16) uint16_t Bs[2][256 * 32];
  int tid = threadIdx.x, lane = tid & 63, wv = tid >> 6;
  int quad = lane >> 4, lr = lane & 15;
  int wm = wv >> 2, wn = wv & 3;                  // 2M x 4N wave grid
  int sl = quad ^ ((lane >> 1) & 3);              // swizzled read slot

  // XCD swizzle: bid&7 = XCD (dispatch round-robin); give it an 8x8 region
  int bid = blockIdx.y * gridDim.x + blockIdx.x;  // 0..511
  int xcd = bid & 7, idx = bid >> 3;              // idx 0..63
  int bx = (xcd & 1) * 8 + (idx & 7);             // 0..15
  int by = (xcd >> 1) * 8 + (idx >> 3);           // 0..31
  int rowT = by * 256, colT = bx * 256;
  int bb = rowT >> 12;

  const uint16_t* aBase = fA + (size_t)rowT * 640;
  const uint16_t* bBase = fB + ((size_t)bb * T_ + colT) * 640;

  int srw = tid >> 2;                              // staging row 0..127
  int k0 = (((tid & 3) ^ ((tid >> 3) & 3))) * 8;   // pre-swizzled src chunk

  f32x4 acc[8][4];
  #pragma unroll
  for (int i = 0; i < 8; ++i)
    #pragma unroll
    for (int j = 0; j < 4; ++j)
      acc[i][j] = (f32x4){0.f, 0.f, 0.f, 0.f};

  auto STAGE = [&](int tile){
    int sb = tile & 1;
    int kc = tile * 32;
    gl_lds16(aBase + (size_t)srw * 640 + kc + k0,         &As[sb][tid * 8]);
    gl_lds16(aBase + (size_t)(128 + srw) * 640 + kc + k0, &As[sb][4096 + tid * 8]);
    gl_lds16(bBase + (size_t)srw * 640 + kc + k0,         &Bs[sb][tid * 8]);
    gl_lds16(bBase + (size_t)(128 + srw) * 640 + kc + k0, &Bs[sb][4096 + tid * 8]);
  };

  // prologue: stage tile 0 into buffer 0
  STAGE(0);
  for (int tile = 0; tile < 20; ++tile){
    int buf = tile & 1;
    if (tile + 1 < 20){
      STAGE(tile + 1);
      // retire tile's 4 loads (oldest); keep tile+1's 4 in flight
      asm volatile("s_waitcnt vmcnt(4)" ::: "memory");
    } else {
      asm volatile("s_waitcnt vmcnt(0)" ::: "memory");
    }
    __builtin_amdgcn_s_barrier();
    bf16x8 bq[4];
    #pragma unroll
    for (int nj = 0; nj < 4; ++nj)
      bq[nj] = *(const bf16x8*)&Bs[buf][(wn*64 + nj*16 + lr) * 32 + sl * 8];
    #pragma unroll
    for (int mi = 0; mi < 8; ++mi){
      bf16x8 aq = *(const bf16x8*)&As[buf][(wm*128 + mi*16 + lr) * 32 + sl * 8];
      #pragma unroll
      for (int nj = 0; nj < 4; ++nj)
        acc[mi][nj] = __builtin_amdgcn_mfma_f32_16x16x32_bf16(bq[nj], aq, acc[mi][nj], 0, 0, 0);
    }
    __builtin_amdgcn_s_barrier();
  }

  float cb = cbias[0];
  #pragma unroll
  for (int mi = 0; mi < 8; ++mi){
    int srow = rowT + wm * 128 + mi * 16 + lr;
    float sv = slin[srow] + cb;
    #pragma unroll
    for (int nj = 0; nj < 4; ++nj){
      int t0 = colT + wn * 64 + nj * 16 + quad * 4;
      F4 tl; tl.v = *(const float4*)(tlin + bb * T_ + t0);
      float o0 = acc[mi][nj][0] + sv + tl.f[0];
      float o1 = acc[mi][nj][1] + sv + tl.f[1];
      float o2 = acc[mi][nj][2] + sv + tl.f[2];
      float o3 = acc[mi][nj][3] + sv + tl.f[3];
      size_t oi = (size_t)srow * T_ + t0;
      if (OUTBF){
        ushort4 pk = make_ushort4(f2bf(o0), f2bf(o1), f2bf(o2), f2bf(o3));
        *(ushort4*)((uint16_t*)outv + oi) = pk;
      } else {
        *(float4*)((float*)outv + oi) = make_float4(o0, o1, o2, o3);
      }
    }
  }
}

// ---- phase 1: flag rows where |ps|*maxT > ZCUT (coalesced, parallel) ----
__global__ void flagrows_k(const float* __restrict__ psT, const float* __restrict__ maxT,
                           uint32_t* __restrict__ rowList, int* __restrict__ rowCnt){
  int w = blockIdx.x, b = blockIdx.y;
  int tid = threadIdx.x;
  float mt = maxT[b * W_ + w];
  const float* psc = psT + (size_t)(b * W_ + w) * S_;
  for (int s = tid; s < S_; s += 256){
    float p = psc[s];
    if (fabsf(p) * mt > ZCUT){
      int k = atomicAdd(rowCnt, 1);
      if (k < ROWCAP)
        rowList[k] = ((uint32_t)b << 19) | ((uint32_t)w << 12) | (uint32_t)s;
    }
  }
}

// ---- phase 2: grid-stride over flagged rows (load-balanced); exact fix
//      merged into d_out ------------------------------------------------
template<int OUTBF>
__global__ __launch_bounds__(256) void fixscan_k(const float* __restrict__ psT,
        const float* __restrict__ ptT, const float* __restrict__ wint,
        const uint16_t* __restrict__ fA, const uint16_t* __restrict__ fB,
        const uint32_t* __restrict__ rowList, const int* __restrict__ rowCnt,
        void* __restrict__ outv){
  int n = *rowCnt; if (n > ROWCAP) n = ROWCAP;
  int tid = threadIdx.x;
  for (int job = blockIdx.x; job < n; job += gridDim.x){
    uint32_t pk = rowList[job];
    int b = (int)(pk >> 19), w = (int)((pk >> 12) & 127u), s = (int)(pk & 4095u);
    float wi = wint[w];
    float p = psT[(size_t)(b * W_ + w) * S_ + s];
    const float* ptc = ptT + (size_t)(b * W_ + w) * T_;
    const uint16_t* fa = fA + ((size_t)b * S_ + s) * 640 + w;
    float a0 = bf2f(fa[0]),   a1 = bf2f(fa[128]), a2 = bf2f(fa[256]);
    float a3 = bf2f(fa[384]), a4 = bf2f(fa[512]);
    for (int t = tid; t < T_; t += 256){
      float q = ptc[t];
      float z = p * q;
      if (fabsf(z) > ZCUT){
        const uint16_t* fb = fB + ((size_t)b * T_ + t) * 640 + w;
        float dot = a0 * bf2f(fb[0]) + a1 * bf2f(fb[128]) + a2 * bf2f(fb[256])
                  + a3 * bf2f(fb[384]) + a4 * bf2f(fb[512]);
        float sil = z / (1.0f + __expf(-z));
        float corr = wi * sil - dot - A0C * wi;
        size_t idx = ((size_t)b * S_ + s) * T_ + t;
        if (OUTBF){
          uint32_t* wp = (uint32_t*)outv + (idx >> 1);
          bool hi = (idx & 1u) != 0;
          uint32_t assumed, old = *wp;
          do {
            assumed = old;
            uint16_t h = hi ? (uint16_t)(assumed >> 16) : (uint16_t)(assumed & 0xFFFFu);
            uint16_t nh = f2bf(bf2f(h) + corr);
            uint32_t nw = hi ? ((assumed & 0x0000FFFFu) | ((uint32_t)nh << 16))
                             : ((assumed & 0xFFFF0000u) | (uint32_t)nh);
            old = atomicCAS(wp, assumed, nw);
          } while (old != assumed);
        } else {
          atomicAdd((float*)outv + idx, corr);
        }
      }
    }
  }
}

extern "C" void kernel_launch(void* const* d_in, const int* in_sizes, int n_in,
                              void* d_out, int out_size, void* d_ws, size_t ws_size,
                              hipStream_t stream){
  char* ws = (char*)d_ws;
  size_t off = 0;
  auto alloc = [&](size_t bytes)->char*{
    char* p = ws + off; off += (bytes + 255) & ~(size_t)255; return p;
  };
  float*    WsT  = (float*)   alloc((size_t)D_*W_*4);
  float*    WtT  = (float*)   alloc((size_t)D_*W_*4);
  float*    wsof = (float*)   alloc(W_*4);
  float*    wtof = (float*)   alloc(W_*4);
  float*    wif  = (float*)   alloc(W_*4);
  float*    cbias= (float*)   alloc(4);
  int*      rowCnt=(int*)     alloc(4);
  uint32_t* rowList=(uint32_t*)alloc((size_t)ROWCAP*4);
  float*    psT  = (float*)   alloc((size_t)B_*S_*W_*4);
  float*    ptT  = (float*)   alloc((size_t)B_*T_*W_*4);
  float*    slin = (float*)   alloc((size_t)B_*S_*4);
  float*    tlin = (float*)   alloc((size_t)B_*T_*4);
  float*    maxT = (float*)   alloc((size_t)B_*W_*4);
  uint16_t* featA= (uint16_t*)alloc((size_t)B_*S_*640*2);
  uint16_t* featB= (uint16_t*)alloc((size_t)B_*T_*640*2);

  // host-side dtype dispatch from byte sizes (fp32 if ambiguous)
  bool inbf  = (in_sizes[0] == (int)((size_t)B_*S_*D_*2));
  bool outbf = (out_size    == (int)((size_t)B_*S_*T_*2));

  if (inbf){
    hipLaunchKernelGGL((prep_k<1>), dim3(32), dim3(256), 0, stream,
        d_in[2], d_in[3], d_in[4], d_in[5], d_in[6], d_in[7],
        WsT, WtT, wsof, wtof, wif, cbias, maxT, rowCnt);
    hipLaunchKernelGGL((proj_k<1>), dim3(1024), dim3(256), 0, stream,
        d_in[0], d_in[1], WsT, WtT, wsof, wtof, wif,
        psT, ptT, slin, tlin, featA, featB, maxT);
  } else {
    hipLaunchKernelGGL((prep_k<0>), dim3(32), dim3(256), 0, stream,
        d_in[2], d_in[3], d_in[4], d_in[5], d_in[6], d_in[7],
        WsT, WtT, wsof, wtof, wif, cbias, maxT, rowCnt);
    hipLaunchKernelGGL((proj_k<0>), dim3(1024), dim3(256), 0, stream,
        d_in[0], d_in[1], WsT, WtT, wsof, wtof, wif,
        psT, ptT, slin, tlin, featA, featB, maxT);
  }
  if (outbf)
    hipLaunchKernelGGL((gemm_k<1>), dim3(T_/256, B_*S_/256), dim3(512), 0, stream,
        featA, featB, slin, tlin, cbias, d_out);
  else
    hipLaunchKernelGGL((gemm_k<0>), dim3(T_/256, B_*S_/256), dim3(512), 0, stream,
        featA, featB, slin, tlin, cbias, d_out);
  hipLaunchKernelGGL(flagrows_k, dim3(W_, B_), dim3(256), 0, stream,
      psT, maxT, rowList, rowCnt);
  if (outbf)
    hipLaunchKernelGGL((fixscan_k<1>), dim3(2048), dim3(256), 0, stream,
        psT, ptT, wif, featA, featB, rowList, rowCnt, d_out);
  else
    hipLaunchKernelGGL((fixscan_k<0>), dim3(2048), dim3(256), 0, stream,
        psT, ptT, wif, featA, featB, rowList, rowCnt, d_out);
}